// Round 3
// baseline (249.920 us; speedup 1.0000x reference)
//
#include <hip/hip_runtime.h>
#include <math.h>

// B=64 rows, T=524288 cols, f32. loss = mean_i ||pred_i - true_i||_2.
// R3: max-occupancy stage1. Halve per-thread buffers (A[4]/B[4] = 32 data
// VGPRs) + __launch_bounds__(256,8) -> VGPR<=64 -> 8 waves/SIMD (32/CU),
// grid 2048 = 8 wg/CU x 256 CU (single residency batch). Doubles TLP for
// ~900-cyc HBM latency hiding vs R2's 4 waves/SIMD.
// Roofline: 268.4 MB read -> ~43 us @ 6.3 TB/s. Harness restore fills
// (~78 us each @ 86% peak) dominate the measured total and are fixed.

#define B_ROWS 64
#define T_ELEMS 524288
#define CHUNKS_PER_ROW 32           // 2048 blocks total
#define BLOCK 256
#define ITERS 4                     // per thread: 4 x 4 f4 per input

typedef float f4 __attribute__((ext_vector_type(4)));

// T/4 = 131072 f4/row/input; per chunk 4096 f4; per thread 16 f4 per input.

__global__ __launch_bounds__(BLOCK, 8) void sdtw_stage1(
    const f4* __restrict__ yp, const f4* __restrict__ yt,
    float* __restrict__ partial)
{
    const int row   = blockIdx.x >> 5;          // / CHUNKS_PER_ROW
    const int chunk = blockIdx.x & (CHUNKS_PER_ROW - 1);
    const int T4        = T_ELEMS / 4;          // 131072
    const int per_chunk = T4 / CHUNKS_PER_ROW;  // 4096 f4
    const size_t base = (size_t)row * T4 + (size_t)chunk * per_chunk
                      + threadIdx.x;

    float acc = 0.0f;
    for (int it = 0; it < ITERS; ++it) {
        const size_t o = base + (size_t)it * (4 * BLOCK);
        f4 A[4], Bv[4];
        // Interleave A/B so in-order vmcnt completion lets the first
        // subtract start early.
#pragma unroll
        for (int j = 0; j < 4; ++j) {
            A[j]  = __builtin_nontemporal_load(&yp[o + (size_t)j * BLOCK]);
            Bv[j] = __builtin_nontemporal_load(&yt[o + (size_t)j * BLOCK]);
        }
        float a0 = 0.0f, a1 = 0.0f;
#pragma unroll
        for (int j = 0; j < 4; ++j) {
            f4 d = A[j] - Bv[j];
            float p = d.x * d.x + d.y * d.y + d.z * d.z + d.w * d.w;
            if (j & 1) a1 += p; else a0 += p;
        }
        acc += a0 + a1;
    }

    // wave-64 shuffle reduction
    for (int off = 32; off > 0; off >>= 1)
        acc += __shfl_down(acc, off, 64);

    __shared__ float s[BLOCK / 64];
    const int lane = threadIdx.x & 63;
    const int wave = threadIdx.x >> 6;
    if (lane == 0) s[wave] = acc;
    __syncthreads();
    if (threadIdx.x == 0) {
        float r = 0.0f;
#pragma unroll
        for (int w = 0; w < BLOCK / 64; ++w) r += s[w];
        partial[blockIdx.x] = r;   // layout: row*CHUNKS_PER_ROW + chunk
    }
}

__global__ __launch_bounds__(64) void sdtw_stage2(
    const float* __restrict__ partial, float* __restrict__ out)
{
    // one wave: thread i handles row i; 32 partials/row read as 8 x f4
    const f4* p4 = (const f4*)partial;           // 512 f4 total
    f4 vs = (f4)0.0f;
#pragma unroll
    for (int k = 0; k < 8; ++k)
        vs += p4[threadIdx.x * 8 + k];
    float accf = (vs.x + vs.y) + (vs.z + vs.w);
    float norm = sqrtf(accf);
    for (int off = 32; off > 0; off >>= 1)
        norm += __shfl_down(norm, off, 64);
    if (threadIdx.x == 0)
        out[0] = norm * (1.0f / (float)B_ROWS);
}

extern "C" void kernel_launch(void* const* d_in, const int* in_sizes, int n_in,
                              void* d_out, int out_size, void* d_ws, size_t ws_size,
                              hipStream_t stream) {
    const f4* yp = (const f4*)d_in[0];
    const f4* yt = (const f4*)d_in[1];
    float* partial = (float*)d_ws;   // 2048 floats = 8 KB
    float* out = (float*)d_out;

    sdtw_stage1<<<B_ROWS * CHUNKS_PER_ROW, BLOCK, 0, stream>>>(yp, yt, partial);
    sdtw_stage2<<<1, 64, 0, stream>>>(partial, out);
}